// Round 4
// baseline (7231.718 us; speedup 1.0000x reference)
//
#include <hip/hip_runtime.h>

// DeformableSliceGrouped on MI355X — R4: DIAGNOSTIC BISECTION BUILD.
// out = BN(w2 @ Mmix(x)) + f,  w2 = o_w@v_w,  x = f + pe,
// M from off/attn from qp = maxpool_hw(q_w @ x).
// b=2, C=256, Z=32, HW=2304.
//
// Changes vs R3 (absmax 7.59 = full-scale -> out_pre uncorrelated garbage):
//  * MFMA GEMMs replaced by trivially-auditable VALU GEMMs (no fragments,
//    no LDS, no in-place aliasing).
//  * xm in its own __device__ global (fp32, 151 MB) — d_ws never touched.
//  * Runtime input-dtype detector (bf16-packed vs fp32) drives all
//    loads/stores: covers the one unverifiable harness assumption.
//  * All internal math fp32.

#define B_   2
#define C_   256
#define Z_   32
#define HW_  2304
#define NSP  73728        // Z_*HW_
#define NBN  147456.0f    // B_*Z_*HW_

typedef unsigned short u16;
typedef unsigned int   u32;

// ---- module-global scratch (d_ws is never used) ----
__device__ int   g_isf32;
__device__ float g_pe[Z_ * C_];
__device__ float g_w2[C_ * C_];
__device__ int   g_qmax[B_ * Z_ * C_];
__device__ float g_M[B_ * Z_ * Z_];
__device__ float g_bn_sum[C_];
__device__ float g_bn_ssq[C_];
__device__ float g_xm[(size_t)B_ * C_ * NSP];   // 151 MB fp32 mixed tensor

__device__ __forceinline__ u16 f2bf(float f) {
  u32 x = __float_as_uint(f);
  x = x + 0x7fffu + ((x >> 16) & 1u);   // RNE
  return (u16)(x >> 16);
}
__device__ __forceinline__ float ldx(const void* p, size_t i, int f32) {
  if (f32) return ((const float*)p)[i];
  return __uint_as_float(((u32)((const u16*)p)[i]) << 16);
}
__device__ __forceinline__ void stx(void* p, size_t i, int f32, float v) {
  if (f32) ((float*)p)[i] = v;
  else     ((u16*)p)[i] = f2bf(v);
}
__device__ __forceinline__ int f2key(float f) {   // order-preserving float->int
  int b = __float_as_int(f);
  return b >= 0 ? b : (b ^ 0x7fffffff);
}
__device__ __forceinline__ float key2f(int k) {
  int b = k >= 0 ? k : (k ^ 0x7fffffff);
  return __int_as_float(b);
}
__device__ __forceinline__ float sane(float v) {  // NaN/Inf -> 0 (bit-level)
  u32 a = __float_as_uint(v) & 0x7fffffffu;
  return (a >= 0x7f800000u) ? 0.f : v;
}
__device__ __forceinline__ float wredmax(float m) {
  m = fmaxf(m, __shfl_xor(m, 1));  m = fmaxf(m, __shfl_xor(m, 2));
  m = fmaxf(m, __shfl_xor(m, 4));  m = fmaxf(m, __shfl_xor(m, 8));
  m = fmaxf(m, __shfl_xor(m, 16)); m = fmaxf(m, __shfl_xor(m, 32));
  return m;
}
__device__ __forceinline__ float wredsum(float s) {
  s += __shfl_xor(s, 1);  s += __shfl_xor(s, 2);  s += __shfl_xor(s, 4);
  s += __shfl_xor(s, 8);  s += __shfl_xor(s, 16); s += __shfl_xor(s, 32);
  return s;
}

// ------------------------------------------------ K00: input dtype detector
// Packed-bf16 feature words: low u16 is a bf16 from ~N(0,1.4) -> exponent
// field in [90,140] essentially always. fp32 words: bits[14:7] are random
// mantissa bits -> ~20% in range. 64 samples separate the two decisively.
__global__ void k00_detect(const void* f) {
  const int t = threadIdx.x;                       // 64 threads
  u32 w = ((const u32*)f)[(size_t)t * 9973u];      // < 640K words: in range either way
  u32 e = (w >> 7) & 0xFFu;
  int in = (e >= 90u && e <= 140u) ? 1 : 0;
  for (int o = 1; o < 64; o <<= 1) in += __shfl_xor(in, o);
  if (t == 0) g_isf32 = (in < 40) ? 1 : 0;
}

// ------------------------------------------------ K0: setup
// blocks 0..255: w2[o][c] = sum_c' o_w[o][c'] * v_w[c'][c]  (fp32)
// block 256: pe table, qmax init (finite key), bn sums zero.
__global__ __launch_bounds__(256) void k0_setup(const void* o_w, const void* v_w) {
  const int f32 = g_isf32;
  const int blk = blockIdx.x, t = threadIdx.x;
  if (blk < 256) {
    float acc = 0.f;
    for (int c = 0; c < 256; ++c)
      acc += ldx(o_w, (size_t)blk * 256 + c, f32) * ldx(v_w, (size_t)c * 256 + t, f32);
    g_w2[blk * 256 + t] = acc;
  } else {
    const int ch = t;
    const float divf = expf(-(float)(ch >> 1) * (9.210340371976184f / 128.0f));
    for (int z = 0; z < Z_; ++z) {
      float arg = (float)z * divf;
      g_pe[z * 256 + ch] = (ch & 1) ? cosf(arg) : sinf(arg);
    }
    const int init_key = f2key(-1e30f);
    for (int k = t; k < B_ * Z_ * 256; k += 256) g_qmax[k] = init_key;
    g_bn_sum[t] = 0.f;
    g_bn_ssq[t] = 0.f;
  }
}

// ------------------------------------------------ K1: q GEMM + hw-maxpool (VALU)
// grid (9, 32, 2) = (n-chunk within z, z, b); thread t = n within chunk.
// q[o][n] = sum_c q_w[o][c] * (f[b][c][n] + pe[z][c]); max over n -> qmax[b][z][o].
__global__ __launch_bounds__(256) void k1_qmax(const void* f, const void* q_w) {
  const int f32 = g_isf32;
  const int t = threadIdx.x;
  const int ch = blockIdx.x, z = blockIdx.y, b = blockIdx.z;
  const size_t xbase = (size_t)(b * C_) * NSP + (size_t)z * HW_ + ch * 256 + t;

  for (int ot = 0; ot < 16; ++ot) {
    float acc[16];
#pragma unroll
    for (int j = 0; j < 16; ++j) acc[j] = 0.f;
    for (int c = 0; c < 256; ++c) {
      float xv = ldx(f, xbase + (size_t)c * NSP, f32) + g_pe[z * C_ + c];
#pragma unroll
      for (int j = 0; j < 16; ++j)
        acc[j] = fmaf(ldx(q_w, (size_t)(ot * 16 + j) * C_ + c, f32), xv, acc[j]);
    }
#pragma unroll
    for (int j = 0; j < 16; ++j) {
      float m = wredmax(acc[j]);
      if ((t & 63) == 0)
        atomicMax(&g_qmax[(b * Z_ + z) * C_ + ot * 16 + j], f2key(m));
    }
  }
}

// ------------------------------------------------ K2: M build (tiny)
__global__ __launch_bounds__(64) void k2_mbuild(
    const void* offs_w, const void* offs_b,
    const void* attn_w, const void* attn_b) {
  const int f32 = g_isf32;
  const int bz = blockIdx.x;           // b*32+z
  const int lane = threadIdx.x;
  float qp[4];
#pragma unroll
  for (int i = 0; i < 4; ++i)
    qp[i] = key2f(g_qmax[bz * 256 + lane * 4 + i]);

  float res[12];
  for (int p = 0; p < 12; ++p) {
    const void* wm = (p < 6) ? offs_w : attn_w;
    const size_t row = (size_t)(p < 6 ? p : p - 6) * 256;
    float s = 0.f;
#pragma unroll
    for (int i = 0; i < 4; ++i) s += qp[i] * ldx(wm, row + lane * 4 + i, f32);
    res[p] = sane(wredsum(s));
  }

  __shared__ float sm[Z_];
  if (lane < Z_) sm[lane] = 0.f;
  __syncthreads();
  if (lane == 0) {
    float att[6], mx = -1e30f;
#pragma unroll
    for (int p = 0; p < 6; ++p) {
      att[p] = sane(res[6 + p] + ldx(attn_b, p, f32));
      mx = fmaxf(mx, att[p]);
    }
    float den = 0.f;
#pragma unroll
    for (int p = 0; p < 6; ++p) { att[p] = expf(att[p] - mx); den += att[p]; }
    float inv = 1.f / den;
#pragma unroll
    for (int p = 0; p < 6; ++p) {
      float a = att[p] * inv;
      float off = sane(res[p] + ldx(offs_b, p, f32));
      off = fminf(fmaxf(off, 0.f), 31.f);
      float lo = floorf(off), hi = ceilf(off), fr = off - lo;
      int il = min(max((int)lo, 0), 31);
      int ih = min(max((int)hi, 0), 31);
      sm[il] += a * (1.f - fr);
      sm[ih] += a * fr;
    }
  }
  __syncthreads();
  if (lane < Z_) g_M[bz * Z_ + lane] = sm[lane];
}

// ------------------------------------------------ K3: z-mixing (VALU)
// g_xm[b][c][zo*HW+hw] = sum_y M[b][zo][y] * (f[b][c][y*HW+hw] + pe[y][c])
// grid 4608 = b(2) * c(256) * hw-chunk(9); thread = hw within chunk.
__global__ __launch_bounds__(256) void k3_mix(const void* f) {
  const int f32 = g_isf32;
  const int id = blockIdx.x;
  const int b = id / 2304;
  const int rem = id % 2304;
  const int c = rem / 9;
  const int hc = rem % 9;
  const int hw = hc * 256 + threadIdx.x;
  const float* Mb = g_M + b * (Z_ * Z_);
  const size_t base = (size_t)(b * C_ + c) * NSP + hw;

  float a[Z_];
#pragma unroll
  for (int zo = 0; zo < Z_; ++zo) a[zo] = 0.f;

  for (int y = 0; y < Z_; ++y) {
    float xv = ldx(f, base + (size_t)y * HW_, f32) + g_pe[y * C_ + c];
#pragma unroll
    for (int zo = 0; zo < Z_; ++zo)
      a[zo] = fmaf(Mb[zo * Z_ + y], xv, a[zo]);
  }
#pragma unroll
  for (int zo = 0; zo < Z_; ++zo)
    g_xm[base + (size_t)zo * HW_] = a[zo];
}

// ------------------------------------------------ K4: out_pre GEMM + BN stats (VALU)
// out_pre[b][o][n] = sum_c w2[o][c] * g_xm[b][c][n] -> d_out, + channel sums.
__global__ __launch_bounds__(256) void k4_gemm(void* outp) {
  const int f32 = g_isf32;
  const int t = threadIdx.x;
  const int ch = blockIdx.x, z = blockIdx.y, b = blockIdx.z;
  const size_t nn = (size_t)z * HW_ + ch * 256 + t;
  const size_t xbase = (size_t)(b * C_) * NSP + nn;

  for (int ot = 0; ot < 16; ++ot) {
    float acc[16];
#pragma unroll
    for (int j = 0; j < 16; ++j) acc[j] = 0.f;
    for (int c = 0; c < 256; ++c) {
      float xv = g_xm[xbase + (size_t)c * NSP];
#pragma unroll
      for (int j = 0; j < 16; ++j)
        acc[j] = fmaf(g_w2[(ot * 16 + j) * C_ + c], xv, acc[j]);
    }
#pragma unroll
    for (int j = 0; j < 16; ++j) {
      const int o = ot * 16 + j;
      float v = sane(acc[j]);
      stx(outp, (size_t)(b * C_ + o) * NSP + nn, f32, v);
      float s  = wredsum(v);
      float ss = wredsum(v * v);
      if ((t & 63) == 0) {
        atomicAdd(&g_bn_sum[o], s);
        atomicAdd(&g_bn_ssq[o], ss);
      }
    }
  }
}

// ------------------------------------------------ K5: BN + residual (in-place)
__global__ __launch_bounds__(256) void k5_final(
    const void* f, void* outp, const void* gamma, const void* beta) {
  const int f32 = g_isf32;
  const size_t e = (size_t)blockIdx.x * 256 + threadIdx.x;
  const int o = (int)((e / NSP) & 255);
  const float mean = g_bn_sum[o] * (1.f / NBN);
  const float var = fmaxf(g_bn_ssq[o] * (1.f / NBN) - mean * mean, 0.f);
  const float rstd = rsqrtf(var + 1e-5f);
  const float sc = ldx(gamma, o, f32) * rstd;
  const float sh = ldx(beta, o, f32) - mean * sc;
  float v = sane(ldx(outp, e, f32) * sc + sh + ldx(f, e, f32));
  stx(outp, e, f32, v);
}

// ------------------------------------------------ launch
extern "C" void kernel_launch(void* const* d_in, const int* in_sizes, int n_in,
                              void* d_out, int out_size, void* d_ws, size_t ws_size,
                              hipStream_t stream)
{
  (void)in_sizes; (void)n_in; (void)out_size; (void)d_ws; (void)ws_size;
  const void* f      = d_in[0];
  const void* q_w    = d_in[1];
  const void* v_w    = d_in[2];
  const void* o_w    = d_in[3];
  const void* offs_w = d_in[4];
  const void* offs_b = d_in[5];
  const void* attn_w = d_in[6];
  const void* attn_b = d_in[7];
  const void* gamma  = d_in[8];
  const void* beta   = d_in[9];

  k00_detect<<<1, 64, 0, stream>>>(f);
  k0_setup<<<257, 256, 0, stream>>>(o_w, v_w);
  k1_qmax<<<dim3(9, 32, 2), 256, 0, stream>>>(f, q_w);
  k2_mbuild<<<64, 64, 0, stream>>>(offs_w, offs_b, attn_w, attn_b);
  k3_mix<<<4608, 256, 0, stream>>>(f);
  k4_gemm<<<dim3(9, 32, 2), 256, 0, stream>>>(d_out);
  k5_final<<<147456, 256, 0, stream>>>(f, d_out, gamma, beta);
}